// Round 8
// baseline (361.468 us; speedup 1.0000x reference)
//
#include <hip/hip_runtime.h>

// BootstrapEnsemble: M=100 MLPs (16 -> 128 -> 4x(128x128) -> {mu, log sigma}),
// shared batch N=16384.
//  1) cvt_weights: one-shot fp32->bf16 (linear, row-major) of x/W1/Wh/Wmu/Wsig
//     into d_ws.
//  2) ens_mlp: fused MFMA MLP. Block = model x 256 rows, 4 waves 2x2 (wk x wn).
//     R8: hidden layers use mfma_f32_32x32x16_bf16 (half the MFMA instrs,
//     2382 vs 2075 TF ceiling), bias rides in the ks=0 MFMA C-operand (no acc
//     init movs), s_setprio(1) around MFMA clusters. Layer 1 + heads stay on
//     the verified 16x16x32 path. LDS h tile [n 0..255][k 0..127] bf16 with
//     XOR swizzle col_elem ^= (row&15)<<3 (row = lane mod 16/32 consistent
//     across both MFMA shapes). Barrier structure = R7 (subtile-split, 2
//     barriers/layer, row-disjoint epilogues).

typedef float  f32x4  __attribute__((ext_vector_type(4)));
typedef float  f32x16 __attribute__((ext_vector_type(16)));
typedef __bf16 bf16x4 __attribute__((ext_vector_type(4)));
typedef __bf16 bf16x8 __attribute__((ext_vector_type(8)));

union BF8 { bf16x8 v; unsigned int ui[4]; };
union BF4 { bf16x4 v; uint2 u2; };

#define MODELS 100
#define NPT    16384
#define HDIM   128
#define SG_OFF (MODELS * NPT)

// d_ws layout (bf16 element offsets), all row-major / linear
#define XB_OFF   0                       // x:    16384 x 16
#define W1B_OFF  262144                  // W1:   100 x 128 x 16
#define WHB_OFF  466944                  // Wh:   100 x 4 x 128 x 128
#define WMU_OFF  7020544                 // Wmu:  100 x 128
#define WSG_OFF  7033344                 // Wsig: 100 x 128

#define GTOT 880768                      // total 8-elem groups

__global__ __launch_bounds__(256) void cvt_weights(
    const float* __restrict__ x,   const float* __restrict__ W1,
    const float* __restrict__ Wh,  const float* __restrict__ Wmu,
    const float* __restrict__ Wsg, unsigned short* __restrict__ ws)
{
  int gid = blockIdx.x * 256 + threadIdx.x;
  if (gid >= GTOT) return;
  const float* src;
  unsigned int dst;
  if (gid < 32768)       { src = x   + gid * 8;                 dst = XB_OFF  + gid * 8; }
  else if (gid < 58368)  { int q = gid - 32768;  src = W1  + q * 8;          dst = W1B_OFF + q * 8; }
  else if (gid < 877568) { int q = gid - 58368;  src = Wh  + (size_t)q * 8;  dst = WHB_OFF + q * 8; }
  else if (gid < 879168) { int q = gid - 877568; src = Wmu + q * 8;          dst = WMU_OFF + q * 8; }
  else                   { int q = gid - 879168; src = Wsg + q * 8;          dst = WSG_OFF + q * 8; }
  f32x4 a = *(const f32x4*)src;
  f32x4 b = *(const f32x4*)(src + 4);
  BF4 lo, hi;
  lo.v = __builtin_convertvector(a, bf16x4);
  hi.v = __builtin_convertvector(b, bf16x4);
  uint4 u; u.x = lo.u2.x; u.y = lo.u2.y; u.z = hi.u2.x; u.w = hi.u2.y;
  *(uint4*)&ws[dst] = u;
}

#define MFMA32(A,B,C) __builtin_amdgcn_mfma_f32_32x32x16_bf16((A),(B),(C),0,0,0)

// epilogue for one 32x32 acc tile: relu + cvt + swizzled b64 LDS writes.
// lane holds D[k_local = (q*4+j pattern)][n = l31]; kbase = wk*64+kt2*32+hi*4.
__device__ __forceinline__ void epilog32(const f32x16& a, unsigned short* hb,
                                         int rr, int l31, int kbase, int cs32) {
  unsigned short* rowp = hb + (rr + l31) * HDIM;
  #pragma unroll
  for (int q = 0; q < 4; ++q) {
    f32x4 v; v[0] = a[q*4+0]; v[1] = a[q*4+1]; v[2] = a[q*4+2]; v[3] = a[q*4+3];
    v = __builtin_elementwise_max(v, f32x4{0.f, 0.f, 0.f, 0.f});
    BF4 b; b.v = __builtin_convertvector(v, bf16x4);
    int col = (kbase + q * 8) ^ cs32;
    *(uint2*)&rowp[col] = b.u2;
  }
}

__global__ __launch_bounds__(256, 2) void ens_mlp(
    const unsigned short* __restrict__ ws,
    const float* __restrict__ b1,  const float* __restrict__ bh,
    const float* __restrict__ bmu, const float* __restrict__ bsg,
    float* __restrict__ out)
{
  __shared__ unsigned short hbuf[256 * HDIM]; // [n 0..255][k 0..127] bf16, swizzled

  // XCD-chunked bijective swizzle: 6400 blocks = 8 XCDs * 800
  const int bid = blockIdx.x;
  const int swz = (bid & 7) * 800 + (bid >> 3);
  const int m   = swz >> 6;            // model 0..99
  const int n0  = (swz & 63) << 8;     // 256-row chunk base

  const int t    = threadIdx.x;
  const int lane = t & 63;
  const int wv   = t >> 6;     // wave 0..3
  const int wk   = wv & 1;     // k_out half
  const int wn   = wv >> 1;    // n half
  // 16x16 indices (layer 1 + heads)
  const int c    = lane & 15;
  const int g    = lane >> 4;
  const int cs   = c << 3;     // elem xor swizzle ((row&15)<<3)
  // 32x32 indices (hidden layers)
  const int l31  = lane & 31;
  const int hi   = lane >> 5;
  const int cs32 = (lane & 15) << 3;   // same swizzle key: row ≡ lane (mod 16)

  const f32x4 zf = {0.0f, 0.0f, 0.0f, 0.0f};

  const unsigned short* whbase = ws + WHB_OFF + (size_t)(m * 4) * (HDIM * HDIM);
  const float* bhm = bh + m * 512;

  // A-fragment banks for hidden layers: [bank][kt2][ks], 4 VGPR each
  BF8 af[2][2][8];

  // load bank 0 (hidden layer 0 weights) early — in flight during layer 1
  #pragma unroll
  for (int kt2 = 0; kt2 < 2; ++kt2)
    #pragma unroll
    for (int ks = 0; ks < 8; ++ks)
      af[0][kt2][ks].v = *(const bf16x8*)&whbase[(wk * 64 + kt2 * 32 + l31) * HDIM + ks * 16 + hi * 8];

  // ---------------- layer 1: 16x16x32, K=16 zero-padded to 32 --------------
  {
    const unsigned short* W1m = ws + W1B_OFF + m * (HDIM * 16);
    const unsigned short* xbp = ws + XB_OFF;
    BF8 a1[4];
    #pragma unroll
    for (int kt = 0; kt < 4; ++kt) {
      if (g < 2) {
        a1[kt].v = *(const bf16x8*)&W1m[(wk * 64 + kt * 16 + c) * 16 + g * 8];
      } else {
        a1[kt].ui[0] = 0u; a1[kt].ui[1] = 0u; a1[kt].ui[2] = 0u; a1[kt].ui[3] = 0u;
      }
    }
    f32x4 bs[4];
    #pragma unroll
    for (int kt = 0; kt < 4; ++kt)
      bs[kt] = *(const f32x4*)(b1 + m * HDIM + (wk * 4 + kt) * 16 + g * 4);

    f32x4 acc1[4][4];
    #pragma unroll
    for (int s = 0; s < 2; ++s) {
      BF8 xb[4];
      #pragma unroll
      for (int nt = 0; nt < 4; ++nt) {
        if (g < 2) {
          xb[nt].v = *(const bf16x8*)&xbp[(n0 + s * 128 + wn * 64 + nt * 16 + c) * 16 + g * 8];
        } else {
          xb[nt].ui[0] = 0u; xb[nt].ui[1] = 0u; xb[nt].ui[2] = 0u; xb[nt].ui[3] = 0u;
        }
      }
      #pragma unroll
      for (int kt = 0; kt < 4; ++kt)
        #pragma unroll
        for (int nt = 0; nt < 4; ++nt)
          acc1[kt][nt] = __builtin_amdgcn_mfma_f32_16x16x32_bf16(a1[kt].v, xb[nt].v, bs[kt], 0, 0, 0);
      #pragma unroll
      for (int kt = 0; kt < 4; ++kt) {
        int col = ((wk * 4 + kt) * 16 + g * 4) ^ cs;
        #pragma unroll
        for (int nt = 0; nt < 4; ++nt) {
          int row = s * 128 + wn * 64 + nt * 16 + c;
          f32x4 v = __builtin_elementwise_max(acc1[kt][nt], zf);
          BF4 b; b.v = __builtin_convertvector(v, bf16x4);
          *(uint2*)&hbuf[row * HDIM + col] = b.u2;
        }
      }
    }
  }
  __syncthreads();

  // ---------------- 4 hidden layers: 32x32x16 ------------------------------
  #pragma unroll
  for (int i = 0; i < 4; ++i) {
    const int cb = i & 1;

    #pragma unroll
    for (int s = 0; s < 2; ++s) {
      // bias vectors (transient; C-operand of the ks=0 MFMA)
      union { f32x16 v; f32x4 q[4]; } bv0, bv1;
      #pragma unroll
      for (int q = 0; q < 4; ++q) {
        bv0.q[q] = *(const f32x4*)(bhm + i * HDIM + wk * 64 +  0 + q * 8 + hi * 4);
        bv1.q[q] = *(const f32x4*)(bhm + i * HDIM + wk * 64 + 32 + q * 8 + hi * 4);
      }
      const int rb = s * 128 + wn * 64;

      f32x16 a00, a01, a10, a11;   // [kt2][nt2]
      __builtin_amdgcn_s_setprio(1);
      #pragma unroll
      for (int ks = 0; ks < 8; ++ks) {
        int e = (ks * 16 + hi * 8) ^ cs32;
        bf16x8 b0 = *(const bf16x8*)&hbuf[(rb +      l31) * HDIM + e];
        bf16x8 b1 = *(const bf16x8*)&hbuf[(rb + 32 + l31) * HDIM + e];
        if (ks == 0) {
          a00 = MFMA32(af[cb][0][0].v, b0, bv0.v);
          a01 = MFMA32(af[cb][0][0].v, b1, bv0.v);
          a10 = MFMA32(af[cb][1][0].v, b0, bv1.v);
          a11 = MFMA32(af[cb][1][0].v, b1, bv1.v);
        } else {
          a00 = MFMA32(af[cb][0][ks].v, b0, a00);
          a01 = MFMA32(af[cb][0][ks].v, b1, a01);
          a10 = MFMA32(af[cb][1][ks].v, b0, a10);
          a11 = MFMA32(af[cb][1][ks].v, b1, a11);
        }
      }
      __builtin_amdgcn_s_setprio(0);

      __syncthreads();   // s=0: all rows 0..127 reads done; s=1: rows 128..255

      // epilogue: write this subtile's rows in place (disjoint from the other
      // subtile's reads)
      epilog32(a00, hbuf, rb,      l31, wk * 64 +  0 + hi * 4, cs32);
      epilog32(a01, hbuf, rb + 32, l31, wk * 64 +  0 + hi * 4, cs32);
      epilog32(a10, hbuf, rb,      l31, wk * 64 + 32 + hi * 4, cs32);
      epilog32(a11, hbuf, rb + 32, l31, wk * 64 + 32 + hi * 4, cs32);

      // prefetch next layer's W fragments into the other bank, hidden under
      // the s=1 compute + epilogue
      if (s == 0 && i < 3) {
        const unsigned short* whn = whbase + (size_t)(i + 1) * (HDIM * HDIM);
        #pragma unroll
        for (int kt2 = 0; kt2 < 2; ++kt2)
          #pragma unroll
          for (int ks = 0; ks < 8; ++ks)
            af[cb ^ 1][kt2][ks].v = *(const bf16x8*)&whn[(wk * 64 + kt2 * 32 + l31) * HDIM + ks * 16 + hi * 8];
      }
    }
  }
  __syncthreads();   // last s=1 epilogue visible before head reads

  // ---------------- heads: mu (D row 0) and log-sigma (D row 1), 16x16 -----
  {
    float bm  = bmu[m];
    float bsv = bsg[m];
    f32x4 acc2[2][2];   // [subtile][nt]
    #pragma unroll
    for (int s = 0; s < 2; ++s)
      #pragma unroll
      for (int nt = 0; nt < 2; ++nt) {
        acc2[s][nt] = zf;
        acc2[s][nt][0] = bm;
        acc2[s][nt][1] = bsv;
      }
    #pragma unroll
    for (int kc = 0; kc < 4; ++kc) {
      BF8 hw;
      if (c < 2) {
        const unsigned short* wp = ws + (c == 0 ? WMU_OFF : WSG_OFF) + m * HDIM + kc * 32 + g * 8;
        hw.v = *(const bf16x8*)wp;
      } else {
        hw.ui[0] = 0u; hw.ui[1] = 0u; hw.ui[2] = 0u; hw.ui[3] = 0u;
      }
      #pragma unroll
      for (int s = 0; s < 2; ++s)
        #pragma unroll
        for (int nt = 0; nt < 2; ++nt) {
          int nl = s * 128 + (wv * 2 + nt) * 16 + c;
          BF8 hf; hf.v = *(const bf16x8*)&hbuf[nl * HDIM + ((kc * 32 + g * 8) ^ cs)];
          acc2[s][nt] = __builtin_amdgcn_mfma_f32_16x16x32_bf16(hw.v, hf.v, acc2[s][nt], 0, 0, 0);
        }
    }
    if (g == 0) {
      #pragma unroll
      for (int s = 0; s < 2; ++s)
        #pragma unroll
        for (int nt = 0; nt < 2; ++nt) {
          int n = n0 + s * 128 + (wv * 2 + nt) * 16 + c;
          out[m * NPT + n]          = acc2[s][nt][0];
          out[SG_OFF + m * NPT + n] = expf(acc2[s][nt][1]);
        }
    }
  }
}

extern "C" void kernel_launch(void* const* d_in, const int* in_sizes, int n_in,
                              void* d_out, int out_size, void* d_ws, size_t ws_size,
                              hipStream_t stream) {
  const float* x   = (const float*)d_in[0];
  const float* W1  = (const float*)d_in[1];
  const float* b1  = (const float*)d_in[2];
  const float* Wh  = (const float*)d_in[3];
  const float* bh  = (const float*)d_in[4];
  const float* Wmu = (const float*)d_in[5];
  const float* bmu = (const float*)d_in[6];
  const float* Wsg = (const float*)d_in[7];
  const float* bsg = (const float*)d_in[8];
  unsigned short* ws = (unsigned short*)d_ws;
  (void)in_sizes; (void)n_in; (void)out_size; (void)ws_size;

  cvt_weights<<<(GTOT + 255) / 256, 256, 0, stream>>>(x, W1, Wh, Wmu, Wsg, ws);
  ens_mlp<<<6400, 256, 0, stream>>>(ws, b1, bh, bmu, bsg, (float*)d_out);
}

// Round 9
// 304.160 us; speedup vs baseline: 1.1884x; 1.1884x over previous
//
#include <hip/hip_runtime.h>

// BootstrapEnsemble: M=100 MLPs (16 -> 128 -> 4x(128x128) -> {mu, log sigma}),
// shared batch N=16384.
//  1) cvt_weights: one-shot fp32->bf16 (linear, row-major) of x/W1/Wh/Wmu/Wsig
//     into d_ws.
//  2) ens_mlp: fused MFMA MLP (R3/R7 skeleton: block = model x 256 rows,
//     4 waves 2x2, swapped-operand mfma_16x16x32_bf16, LDS XOR swizzle
//     col ^= (row&15)<<3, subtile-split barrier structure). R9:
//       - cross-layer W prefetch PINNED by asm volatile("" ::: "memory")
//         right after the load batch: ws is __restrict so the compiler could
//         legally sink/re-materialize the loads to their use site (R7/R8
//         evidence: VGPR stuck at 128); the memory clobber forbids moving
//         loads across it, forcing register residency + early issue.
//       - bias rides in the kc==0 MFMA C-operand (no acc-init v_movs).

typedef float  f32x4  __attribute__((ext_vector_type(4)));
typedef __bf16 bf16x4 __attribute__((ext_vector_type(4)));
typedef __bf16 bf16x8 __attribute__((ext_vector_type(8)));

union BF8 { bf16x8 v; unsigned int ui[4]; };
union BF4 { bf16x4 v; uint2 u2; };

#define MODELS 100
#define NPT    16384
#define HDIM   128
#define SG_OFF (MODELS * NPT)

// d_ws layout (bf16 element offsets), all row-major / linear
#define XB_OFF   0                       // x:    16384 x 16
#define W1B_OFF  262144                  // W1:   100 x 128 x 16
#define WHB_OFF  466944                  // Wh:   100 x 4 x 128 x 128
#define WMU_OFF  7020544                 // Wmu:  100 x 128
#define WSG_OFF  7033344                 // Wsig: 100 x 128

#define GTOT 880768                      // total 8-elem groups

__global__ __launch_bounds__(256) void cvt_weights(
    const float* __restrict__ x,   const float* __restrict__ W1,
    const float* __restrict__ Wh,  const float* __restrict__ Wmu,
    const float* __restrict__ Wsg, unsigned short* __restrict__ ws)
{
  int gid = blockIdx.x * 256 + threadIdx.x;
  if (gid >= GTOT) return;
  const float* src;
  unsigned int dst;
  if (gid < 32768)       { src = x   + gid * 8;                 dst = XB_OFF  + gid * 8; }
  else if (gid < 58368)  { int q = gid - 32768;  src = W1  + q * 8;          dst = W1B_OFF + q * 8; }
  else if (gid < 877568) { int q = gid - 58368;  src = Wh  + (size_t)q * 8;  dst = WHB_OFF + q * 8; }
  else if (gid < 879168) { int q = gid - 877568; src = Wmu + q * 8;          dst = WMU_OFF + q * 8; }
  else                   { int q = gid - 879168; src = Wsg + q * 8;          dst = WSG_OFF + q * 8; }
  f32x4 a = *(const f32x4*)src;
  f32x4 b = *(const f32x4*)(src + 4);
  BF4 lo, hi;
  lo.v = __builtin_convertvector(a, bf16x4);
  hi.v = __builtin_convertvector(b, bf16x4);
  uint4 u; u.x = lo.u2.x; u.y = lo.u2.y; u.z = hi.u2.x; u.w = hi.u2.y;
  *(uint4*)&ws[dst] = u;
}

__global__ __launch_bounds__(256, 2) void ens_mlp(
    const unsigned short* __restrict__ ws,
    const float* __restrict__ b1,  const float* __restrict__ bh,
    const float* __restrict__ bmu, const float* __restrict__ bsg,
    float* __restrict__ out)
{
  __shared__ unsigned short hbuf[256 * HDIM]; // [n 0..255][h 0..127] bf16, swizzled

  // XCD-chunked bijective swizzle: 6400 blocks = 8 XCDs * 800
  const int bid = blockIdx.x;
  const int swz = (bid & 7) * 800 + (bid >> 3);
  const int m   = swz >> 6;            // model 0..99
  const int n0  = (swz & 63) << 8;     // 256-row chunk base

  const int t    = threadIdx.x;
  const int lane = t & 63;
  const int wv   = t >> 6;     // wave 0..3
  const int wk   = wv & 1;     // k_out half
  const int wn   = wv >> 1;    // n half
  const int c    = lane & 15;  // frag row (A: k_out, B: n) / D col (n)
  const int g    = lane >> 4;  // frag k-group / D row group
  const int cs   = c << 3;     // xor swizzle ((row&15)<<3)

  const f32x4 zf = {0.0f, 0.0f, 0.0f, 0.0f};

  f32x4 acc[4][4];      // [kt][nt] -- one subtile live at a time
  BF8   afb[2][4][4];   // double-banked W fragments [bank][kt][kc]

  const unsigned short* whbase = ws + WHB_OFF + (size_t)(m * 4) * (HDIM * HDIM);

  // ---- issue layer-0 hidden-weight loads FIRST (in flight during layer 1) --
  #pragma unroll
  for (int kt = 0; kt < 4; ++kt)
    #pragma unroll
    for (int kc = 0; kc < 4; ++kc)
      afb[0][kt][kc].v = *(const bf16x8*)&whbase[(wk * 64 + kt * 16 + c) * HDIM + kc * 32 + g * 8];
  asm volatile("" ::: "memory");   // pin: loads may not sink below this point

  // ---------------- layer 1 (K=16 zero-padded to 32) -----------------------
  {
    const unsigned short* W1m = ws + W1B_OFF + m * (HDIM * 16);
    const unsigned short* xbp = ws + XB_OFF;
    BF8 a1[4];
    #pragma unroll
    for (int kt = 0; kt < 4; ++kt) {
      if (g < 2) {
        a1[kt].v = *(const bf16x8*)&W1m[(wk * 64 + kt * 16 + c) * 16 + g * 8];
      } else {
        a1[kt].ui[0] = 0u; a1[kt].ui[1] = 0u; a1[kt].ui[2] = 0u; a1[kt].ui[3] = 0u;
      }
    }
    f32x4 bs[4];
    #pragma unroll
    for (int kt = 0; kt < 4; ++kt)
      bs[kt] = *(const f32x4*)(b1 + m * HDIM + (wk * 4 + kt) * 16 + g * 4);

    #pragma unroll
    for (int s = 0; s < 2; ++s) {
      BF8 xb[4];
      #pragma unroll
      for (int nt = 0; nt < 4; ++nt) {
        if (g < 2) {
          xb[nt].v = *(const bf16x8*)&xbp[(n0 + s * 128 + wn * 64 + nt * 16 + c) * 16 + g * 8];
        } else {
          xb[nt].ui[0] = 0u; xb[nt].ui[1] = 0u; xb[nt].ui[2] = 0u; xb[nt].ui[3] = 0u;
        }
      }
      #pragma unroll
      for (int kt = 0; kt < 4; ++kt)
        #pragma unroll
        for (int nt = 0; nt < 4; ++nt)
          acc[kt][nt] = __builtin_amdgcn_mfma_f32_16x16x32_bf16(a1[kt].v, xb[nt].v, bs[kt], 0, 0, 0);
      // epilogue: relu + cvt -> hbuf (first writes; no barrier needed before)
      #pragma unroll
      for (int kt = 0; kt < 4; ++kt) {
        int col = ((wk * 4 + kt) * 16 + g * 4) ^ cs;
        #pragma unroll
        for (int nt = 0; nt < 4; ++nt) {
          int row = s * 128 + wn * 64 + nt * 16 + c;
          f32x4 v = __builtin_elementwise_max(acc[kt][nt], zf);
          BF4 b; b.v = __builtin_convertvector(v, bf16x4);
          *(uint2*)&hbuf[row * HDIM + col] = b.u2;
        }
      }
    }
  }
  __syncthreads();

  // ---------------- 4 hidden layers ----------------------------------------
  #pragma unroll
  for (int i = 0; i < 4; ++i) {
    const int cur = i & 1;
    const int nxt = cur ^ 1;

    // bias loads (issued early, held in regs)
    f32x4 bs[4];
    #pragma unroll
    for (int kt = 0; kt < 4; ++kt)
      bs[kt] = *(const f32x4*)(bh + m * 512 + i * HDIM + (wk * 4 + kt) * 16 + g * 4);

    // prefetch next layer's W fragments into the other bank, then PIN them:
    // the memory clobber forbids sinking/re-materializing these loads below,
    // so their latency hides under this layer's compute.
    if (i < 3) {
      const unsigned short* whn = whbase + (size_t)(i + 1) * (HDIM * HDIM);
      #pragma unroll
      for (int kt = 0; kt < 4; ++kt)
        #pragma unroll
        for (int kc = 0; kc < 4; ++kc)
          afb[nxt][kt][kc].v = *(const bf16x8*)&whn[(wk * 64 + kt * 16 + c) * HDIM + kc * 32 + g * 8];
    }
    asm volatile("" ::: "memory");

    // ---- s = 0: compute rows 0..127 (bias enters as kc==0 C-operand) ----
    #pragma unroll
    for (int kc = 0; kc < 4; ++kc) {
      BF8 bf[4];
      #pragma unroll
      for (int nt = 0; nt < 4; ++nt)
        bf[nt].v = *(const bf16x8*)&hbuf[(wn * 64 + nt * 16 + c) * HDIM + ((kc * 32 + g * 8) ^ cs)];
      #pragma unroll
      for (int kt = 0; kt < 4; ++kt)
        #pragma unroll
        for (int nt = 0; nt < 4; ++nt)
          acc[kt][nt] = __builtin_amdgcn_mfma_f32_16x16x32_bf16(
              afb[cur][kt][kc].v, bf[nt].v, (kc == 0 ? bs[kt] : acc[kt][nt]), 0, 0, 0);
    }
    __syncthreads();   // all s=0 reads done (rows 0..127)

    // s=0 epilogue: write rows 0..127 in place (disjoint from s=1's reads)
    #pragma unroll
    for (int kt = 0; kt < 4; ++kt) {
      int col = ((wk * 4 + kt) * 16 + g * 4) ^ cs;
      #pragma unroll
      for (int nt = 0; nt < 4; ++nt) {
        int row = wn * 64 + nt * 16 + c;
        f32x4 v = __builtin_elementwise_max(acc[kt][nt], zf);
        BF4 b; b.v = __builtin_convertvector(v, bf16x4);
        *(uint2*)&hbuf[row * HDIM + col] = b.u2;
      }
    }

    // ---- s = 1: compute rows 128..255 ----
    #pragma unroll
    for (int kc = 0; kc < 4; ++kc) {
      BF8 bf[4];
      #pragma unroll
      for (int nt = 0; nt < 4; ++nt)
        bf[nt].v = *(const bf16x8*)&hbuf[(128 + wn * 64 + nt * 16 + c) * HDIM + ((kc * 32 + g * 8) ^ cs)];
      #pragma unroll
      for (int kt = 0; kt < 4; ++kt)
        #pragma unroll
        for (int nt = 0; nt < 4; ++nt)
          acc[kt][nt] = __builtin_amdgcn_mfma_f32_16x16x32_bf16(
              afb[cur][kt][kc].v, bf[nt].v, (kc == 0 ? bs[kt] : acc[kt][nt]), 0, 0, 0);
    }
    __syncthreads();   // all s=1 reads done (rows 128..255)

    // s=1 epilogue: write rows 128..255 in place
    #pragma unroll
    for (int kt = 0; kt < 4; ++kt) {
      int col = ((wk * 4 + kt) * 16 + g * 4) ^ cs;
      #pragma unroll
      for (int nt = 0; nt < 4; ++nt) {
        int row = 128 + wn * 64 + nt * 16 + c;
        f32x4 v = __builtin_elementwise_max(acc[kt][nt], zf);
        BF4 b; b.v = __builtin_convertvector(v, bf16x4);
        *(uint2*)&hbuf[row * HDIM + col] = b.u2;
      }
    }
  }
  __syncthreads();   // s=1 epilogue of layer 3 visible before head reads

  // ---------------- heads: mu (D row 0) and log-sigma (D row 1) ------------
  {
    float bm  = bmu[m];
    float bsv = bsg[m];
    f32x4 acc2[2][2];   // [subtile][nt]
    #pragma unroll
    for (int s = 0; s < 2; ++s)
      #pragma unroll
      for (int nt = 0; nt < 2; ++nt) {
        acc2[s][nt] = zf;
        acc2[s][nt][0] = bm;
        acc2[s][nt][1] = bsv;
      }
    #pragma unroll
    for (int kc = 0; kc < 4; ++kc) {
      BF8 hw;
      if (c < 2) {
        const unsigned short* wp = ws + (c == 0 ? WMU_OFF : WSG_OFF) + m * HDIM + kc * 32 + g * 8;
        hw.v = *(const bf16x8*)wp;
      } else {
        hw.ui[0] = 0u; hw.ui[1] = 0u; hw.ui[2] = 0u; hw.ui[3] = 0u;
      }
      #pragma unroll
      for (int s = 0; s < 2; ++s)
        #pragma unroll
        for (int nt = 0; nt < 2; ++nt) {
          int nl = s * 128 + (wv * 2 + nt) * 16 + c;
          BF8 hf; hf.v = *(const bf16x8*)&hbuf[nl * HDIM + ((kc * 32 + g * 8) ^ cs)];
          acc2[s][nt] = __builtin_amdgcn_mfma_f32_16x16x32_bf16(hw.v, hf.v, acc2[s][nt], 0, 0, 0);
        }
    }
    if (g == 0) {
      #pragma unroll
      for (int s = 0; s < 2; ++s)
        #pragma unroll
        for (int nt = 0; nt < 2; ++nt) {
          int n = n0 + s * 128 + (wv * 2 + nt) * 16 + c;
          out[m * NPT + n]          = acc2[s][nt][0];
          out[SG_OFF + m * NPT + n] = expf(acc2[s][nt][1]);
        }
    }
  }
}

extern "C" void kernel_launch(void* const* d_in, const int* in_sizes, int n_in,
                              void* d_out, int out_size, void* d_ws, size_t ws_size,
                              hipStream_t stream) {
  const float* x   = (const float*)d_in[0];
  const float* W1  = (const float*)d_in[1];
  const float* b1  = (const float*)d_in[2];
  const float* Wh  = (const float*)d_in[3];
  const float* bh  = (const float*)d_in[4];
  const float* Wmu = (const float*)d_in[5];
  const float* bmu = (const float*)d_in[6];
  const float* Wsg = (const float*)d_in[7];
  const float* bsg = (const float*)d_in[8];
  unsigned short* ws = (unsigned short*)d_ws;
  (void)in_sizes; (void)n_in; (void)out_size; (void)ws_size;

  cvt_weights<<<(GTOT + 255) / 256, 256, 0, stream>>>(x, W1, Wh, Wmu, Wsg, ws);
  ens_mlp<<<6400, 256, 0, stream>>>(ws, b1, bh, bmu, bsg, (float*)d_out);
}

// Round 10
// 228.858 us; speedup vs baseline: 1.5794x; 1.3290x over previous
//
#include <hip/hip_runtime.h>

// BootstrapEnsemble: M=100 MLPs (16 -> 128 -> 4x(128x128) -> {mu, log sigma}),
// shared batch N=16384.
//  1) cvt_weights: one-shot fp32->bf16 of x/W1/Wh/Wmu/Wsig into d_ws. Wh is
//     PRE-SWIZZLED (8-elem group j at col 8*(j ^ (row&7))) so the main kernel
//     stages it linearly via global_load_lds and reads A-frags conflict-free.
//  2) ens_mlp: register-resident-h MLP. Block = (model, 512 rows), 8 waves,
//     each wave owns a private 64-row n-band and computes ALL 128 k_out ->
//     h never leaves registers. Layer-to-layer B-frag rebuild: relu + cvt_pk
//     (via convertvector) + v_permlane32_swap_b32 (VALU pipe, T12). All 4
//     hidden W layers (128 KB) staged to LDS ONCE per block (overlapped with
//     layer 1); ONE barrier total, waves free-run after it. Hidden layers on
//     mfma_f32_32x32x16_bf16 (layouts empirically validated by R8).

typedef float  f32x4  __attribute__((ext_vector_type(4)));
typedef float  f32x16 __attribute__((ext_vector_type(16)));
typedef __bf16 bf16x4 __attribute__((ext_vector_type(4)));
typedef __bf16 bf16x8 __attribute__((ext_vector_type(8)));

union BF4  { bf16x4 v; uint2 u2; };
union FRAG { bf16x8 v; uint4 u4; };

#define MODELS 100
#define NPT    16384
#define HDIM   128
#define SG_OFF (MODELS * NPT)

// d_ws layout (bf16 element offsets)
#define XB_OFF   0                       // x:    16384 x 16 (linear)
#define W1B_OFF  262144                  // W1:   100 x 128 x 16 (linear)
#define WHB_OFF  466944                  // Wh:   100 x 4 x 128 x 128 (SWIZZLED)
#define WMU_OFF  7020544                 // Wmu:  100 x 128 (linear)
#define WSG_OFF  7033344                 // Wsig: 100 x 128 (linear)

#define GTOT 880768                      // total 8-elem groups

__global__ __launch_bounds__(256) void cvt_weights(
    const float* __restrict__ x,   const float* __restrict__ W1,
    const float* __restrict__ Wh,  const float* __restrict__ Wmu,
    const float* __restrict__ Wsg, unsigned short* __restrict__ ws)
{
  int gid = blockIdx.x * 256 + threadIdx.x;
  if (gid >= GTOT) return;
  const float* src;
  unsigned int dst;
  if (gid < 32768) {
    src = x + gid * 8;                       dst = XB_OFF + gid * 8;
  } else if (gid < 58368) {
    int g = gid - 32768;
    src = W1 + g * 8;                        dst = W1B_OFF + g * 8;
  } else if (gid < 877568) {
    int g = gid - 58368;
    int chunk  = g >> 11;                    // m*4 + layer
    int within = g & 2047;
    int r   = within >> 4;                   // k_out row
    int col = ((within & 15) * 8) ^ ((r & 7) << 3);  // swizzled 8-group
    src = Wh + (size_t)g * 8;
    dst = WHB_OFF + chunk * 16384 + r * HDIM + col;
  } else if (gid < 879168) {
    int g = gid - 877568;
    src = Wmu + g * 8;                       dst = WMU_OFF + g * 8;
  } else {
    int g = gid - 879168;
    src = Wsg + g * 8;                       dst = WSG_OFF + g * 8;
  }
  f32x4 a = *(const f32x4*)src;
  f32x4 b = *(const f32x4*)(src + 4);
  BF4 lo, hi;
  lo.v = __builtin_convertvector(a, bf16x4);
  hi.v = __builtin_convertvector(b, bf16x4);
  uint4 u; u.x = lo.u2.x; u.y = lo.u2.y; u.z = hi.u2.x; u.w = hi.u2.y;
  *(uint4*)&ws[dst] = u;
}

__device__ __forceinline__ void gload_lds16(const void* g, void* l) {
  __builtin_amdgcn_global_load_lds(
      (const __attribute__((address_space(1))) void*)g,
      (__attribute__((address_space(3))) void*)l, 16, 0, 0);
}

#define MFMA32(A,B,C) __builtin_amdgcn_mfma_f32_32x32x16_bf16((A),(B),(C),0,0,0)

// D (f32x16, per lane: col n = l31, row k' = 32*kt2 + 8*(reg>>2) + 4*hi + (reg&3))
// -> next-layer B-frags (lane holds h[n=l31][k = 16*ks + 8*hi + 0..7]).
// P[q] = packed bf16 pair-of-pairs of relu(acc quad q); for sb in {0,1}:
// swap(P[2sb].t, P[2sb+1].t) gives {u0,u2},{u1,u3}; frag[2*kt2+sb]={u0,u1,u2,u3}.
__device__ __forceinline__ void build_hfrag(const f32x16 (&acc)[2][4],
                                            uint4 (&hf)[2][8]) {
  const f32x4 zf = {0.0f, 0.0f, 0.0f, 0.0f};
  #pragma unroll
  for (int nt = 0; nt < 2; ++nt) {
    #pragma unroll
    for (int kt2 = 0; kt2 < 4; ++kt2) {
      uint2 P[4];
      #pragma unroll
      for (int q = 0; q < 4; ++q) {
        f32x4 v;
        v[0] = acc[nt][kt2][4*q+0]; v[1] = acc[nt][kt2][4*q+1];
        v[2] = acc[nt][kt2][4*q+2]; v[3] = acc[nt][kt2][4*q+3];
        v = __builtin_elementwise_max(v, zf);
        BF4 b; b.v = __builtin_convertvector(v, bf16x4);
        P[q] = b.u2;
      }
      #pragma unroll
      for (int sb = 0; sb < 2; ++sb) {
        unsigned int x0 = P[2*sb].x, y0 = P[2*sb+1].x;
        unsigned int x1 = P[2*sb].y, y1 = P[2*sb+1].y;
        asm("v_permlane32_swap_b32 %0, %1" : "+v"(x0), "+v"(y0));
        asm("v_permlane32_swap_b32 %0, %1" : "+v"(x1), "+v"(y1));
        uint4 f; f.x = x0; f.y = x1; f.z = y0; f.w = y1;
        hf[nt][2*kt2+sb] = f;
      }
    }
  }
}

__global__ __launch_bounds__(512, 2) void ens_mlp(
    const unsigned short* __restrict__ ws,
    const float* __restrict__ b1,  const float* __restrict__ bh,
    const float* __restrict__ bmu, const float* __restrict__ bsg,
    float* __restrict__ out)
{
  __shared__ unsigned short wlds[4 * HDIM * HDIM];   // 128 KB, all hidden W

  // XCD-chunked bijective swizzle: 3200 blocks = 8 XCDs * 400
  const int bid = blockIdx.x;
  const int swz = (bid & 7) * 400 + (bid >> 3);
  const int m   = swz >> 5;            // model 0..99
  const int nb0 = (swz & 31) << 9;     // 512-row chunk base

  const int t    = threadIdx.x;
  const int lane = t & 63;
  const int wv   = t >> 6;             // wave 0..7
  const int l31  = lane & 31;
  const int hi   = lane >> 5;
  const int nbw  = nb0 + wv * 64;      // this wave's private 64-row band

  // ---- stage all hidden W (pre-swizzled image) into LDS, async ----------
  {
    const char* src = (const char*)(ws + WHB_OFF + m * 65536);
    char* dst = (char*)wlds;
    #pragma unroll
    for (int it = 0; it < 16; ++it) {
      int off = t * 16 + it * 8192;
      gload_lds16(src + off, dst + off);
    }
  }

  uint4  hfrag[2][8];   // h B-frags: [nt][ks], lane holds h[n][16ks+8hi+0..7]
  f32x16 acc[2][4];     // [nt][kt2]

  // ---- layer 1: K=16, exact (no padding) ---------------------------------
  {
    const unsigned short* W1m = ws + W1B_OFF + m * (HDIM * 16);
    const unsigned short* xp  = ws + XB_OFF;
    FRAG w1f[4], xf[2];
    #pragma unroll
    for (int kt2 = 0; kt2 < 4; ++kt2)
      w1f[kt2].v = *(const bf16x8*)&W1m[(kt2 * 32 + l31) * 16 + hi * 8];
    #pragma unroll
    for (int nt = 0; nt < 2; ++nt)
      xf[nt].v = *(const bf16x8*)&xp[(nbw + nt * 32 + l31) * 16 + hi * 8];
    #pragma unroll
    for (int kt2 = 0; kt2 < 4; ++kt2) {
      union { f32x16 v; f32x4 q[4]; } C;
      #pragma unroll
      for (int q = 0; q < 4; ++q)
        C.q[q] = *(const f32x4*)(b1 + m * HDIM + kt2 * 32 + q * 8 + hi * 4);
      #pragma unroll
      for (int nt = 0; nt < 2; ++nt)
        acc[nt][kt2] = MFMA32(w1f[kt2].v, xf[nt].v, C.v);
    }
  }
  build_hfrag(acc, hfrag);

  __syncthreads();   // staging DMA complete; ONLY barrier in the kernel

  // ---- 4 hidden layers: h register-resident, W from LDS ------------------
  #pragma unroll
  for (int i = 0; i < 4; ++i) {
    const char* wl = (const char*)wlds + i * 32768;
    const float* bp = bh + m * 512 + i * HDIM;

    union { f32x16 v; f32x4 q[4]; } C[4];
    #pragma unroll
    for (int kt2 = 0; kt2 < 4; ++kt2)
      #pragma unroll
      for (int q = 0; q < 4; ++q)
        C[kt2].q[q] = *(const f32x4*)(bp + kt2 * 32 + q * 8 + hi * 4);

    #pragma unroll
    for (int ks = 0; ks < 8; ++ks) {
      FRAG wf[4];
      #pragma unroll
      for (int kt2 = 0; kt2 < 4; ++kt2) {
        int off = (kt2 * 32 + l31) * 256 + ((ks * 32 + hi * 16) ^ ((l31 & 7) << 4));
        wf[kt2].u4 = *(const uint4*)(wl + off);
      }
      #pragma unroll
      for (int kt2 = 0; kt2 < 4; ++kt2)
        #pragma unroll
        for (int nt = 0; nt < 2; ++nt) {
          FRAG hv; hv.u4 = hfrag[nt][ks];
          acc[nt][kt2] = MFMA32(wf[kt2].v, hv.v,
                                ks == 0 ? C[kt2].v : acc[nt][kt2]);
        }
    }
    build_hfrag(acc, hfrag);
  }

  // ---- heads: mu (k'=0) and log-sigma (k'=1) ------------------------------
  {
    FRAG hw[8];
    const unsigned short* wp = ws + (l31 == 0 ? WMU_OFF : WSG_OFF) + m * HDIM;
    #pragma unroll
    for (int ks = 0; ks < 8; ++ks) {
      if (l31 < 2) {
        hw[ks].v = *(const bf16x8*)&wp[ks * 16 + hi * 8];
      } else {
        uint4 z; z.x = 0u; z.y = 0u; z.z = 0u; z.w = 0u;
        hw[ks].u4 = z;
      }
    }
    f32x16 C;
    #pragma unroll
    for (int j = 0; j < 16; ++j) C[j] = 0.0f;
    if (hi == 0) { C[0] = bmu[m]; C[1] = bsg[m]; }

    #pragma unroll
    for (int nt = 0; nt < 2; ++nt) {
      f32x16 a2;
      #pragma unroll
      for (int ks = 0; ks < 8; ++ks) {
        FRAG hv; hv.u4 = hfrag[nt][ks];
        a2 = MFMA32(hw[ks].v, hv.v, ks == 0 ? C : a2);
      }
      if (hi == 0) {
        int n = nbw + nt * 32 + l31;
        out[m * NPT + n]          = a2[0];
        out[SG_OFF + m * NPT + n] = expf(a2[1]);
      }
    }
  }
}

extern "C" void kernel_launch(void* const* d_in, const int* in_sizes, int n_in,
                              void* d_out, int out_size, void* d_ws, size_t ws_size,
                              hipStream_t stream) {
  const float* x   = (const float*)d_in[0];
  const float* W1  = (const float*)d_in[1];
  const float* b1  = (const float*)d_in[2];
  const float* Wh  = (const float*)d_in[3];
  const float* bh  = (const float*)d_in[4];
  const float* Wmu = (const float*)d_in[5];
  const float* bmu = (const float*)d_in[6];
  const float* Wsg = (const float*)d_in[7];
  const float* bsg = (const float*)d_in[8];
  unsigned short* ws = (unsigned short*)d_ws;
  (void)in_sizes; (void)n_in; (void)out_size; (void)ws_size;

  cvt_weights<<<(GTOT + 255) / 256, 256, 0, stream>>>(x, W1, Wh, Wmu, Wsg, ws);
  ens_mlp<<<3200, 512, 0, stream>>>(ws, b1, bh, bmu, bsg, (float*)d_out);
}